// Round 5
// baseline (223.648 us; speedup 1.0000x reference)
//
#include <hip/hip_runtime.h>
#include <hip/hip_bf16.h>

typedef float f32x4 __attribute__((ext_vector_type(4)));
typedef unsigned short u16;
typedef unsigned int   u32;
typedef u16 u16x4 __attribute__((ext_vector_type(4)));
typedef u16 u16x8 __attribute__((ext_vector_type(8)));

#define D4  32  // D=128 floats = 32 float4 per row
#define D16 16  // D=128 bf16   = 16 u16x8 per row

__device__ __forceinline__ float softplus_f(float r) {
    return (r > 20.0f) ? r : log1pf(__expf(r));
}
__device__ __forceinline__ float clip10(float e) {
    return fminf(fmaxf(e, -10.0f), 10.0f);
}
__device__ __forceinline__ u16 f32_to_bf16_rne(float f) {
    u32 b = __float_as_uint(f);
    b += 0x7FFFu + ((b >> 16) & 1u);   // round-to-nearest-even
    return (u16)(b >> 16);
}
__device__ __forceinline__ float bf16_to_f32(u16 h) {
    return __uint_as_float(((u32)h) << 16);
}

// Pass 1: tab[i] = bf16( mu[i] + softplus(rho[i]) * clip(eps[i]) ), 8 elems/thread.
__global__ __launch_bounds__(256) void sample_table_bf16_kernel(
    const f32x4* __restrict__ mu,
    const f32x4* __restrict__ rho,
    const f32x4* __restrict__ eps,
    u16x4* __restrict__ tab,
    long n4)
{
    long t  = (long)blockIdx.x * blockDim.x + threadIdx.x;
    long j0 = t * 2, j1 = j0 + 1;
    if (j0 >= n4) return;

    f32x4 m0 = __builtin_nontemporal_load(&mu[j0]);
    f32x4 r0 = __builtin_nontemporal_load(&rho[j0]);
    f32x4 e0 = __builtin_nontemporal_load(&eps[j0]);

    u16x4 o0;
    o0.x = f32_to_bf16_rne(m0.x + softplus_f(r0.x) * clip10(e0.x));
    o0.y = f32_to_bf16_rne(m0.y + softplus_f(r0.y) * clip10(e0.y));
    o0.z = f32_to_bf16_rne(m0.z + softplus_f(r0.z) * clip10(e0.z));
    o0.w = f32_to_bf16_rne(m0.w + softplus_f(r0.w) * clip10(e0.w));

    if (j1 < n4) {
        f32x4 m1 = __builtin_nontemporal_load(&mu[j1]);
        f32x4 r1 = __builtin_nontemporal_load(&rho[j1]);
        f32x4 e1 = __builtin_nontemporal_load(&eps[j1]);
        u16x8 o;
        o[0] = o0.x; o[1] = o0.y; o[2] = o0.z; o[3] = o0.w;
        o[4] = f32_to_bf16_rne(m1.x + softplus_f(r1.x) * clip10(e1.x));
        o[5] = f32_to_bf16_rne(m1.y + softplus_f(r1.y) * clip10(e1.y));
        o[6] = f32_to_bf16_rne(m1.z + softplus_f(r1.z) * clip10(e1.z));
        o[7] = f32_to_bf16_rne(m1.w + softplus_f(r1.w) * clip10(e1.w));
        *(u16x8*)&tab[j0] = o;           // one 16 B store
    } else {
        tab[j0] = o0;
    }
}

// Pass 2: out[row,:] = f32(tab[x[row],:]).
// 16 lanes per row, 16 B gather per lane (u16x8), 4 rows per thread for MLP.
// All 4 x-loads then all 4 gathers issue before any conversion/store.
__global__ __launch_bounds__(256) void gather_bf16_kernel(
    const int* __restrict__ x,
    const u16x8* __restrict__ tab,
    f32x4* __restrict__ out,
    int n_rows, int S)
{
    int g    = blockIdx.x * blockDim.x + threadIdx.x;
    int slot = g >> 4;        // 16 lanes per row
    int lane = g & 15;
    if (slot >= S) return;

    int  r0 = slot,       r1 = slot + S,   r2 = slot + 2*S, r3 = slot + 3*S;
    bool h1 = (r1 < n_rows), h2 = (r2 < n_rows), h3 = (r3 < n_rows);

    int v0 = x[r0];
    int v1 = h1 ? x[r1] : v0;
    int v2 = h2 ? x[r2] : v0;
    int v3 = h3 ? x[r3] : v0;

    u16x8 t0 = tab[(long)v0 * D16 + lane];
    u16x8 t1 = tab[(long)v1 * D16 + lane];
    u16x8 t2 = tab[(long)v2 * D16 + lane];
    u16x8 t3 = tab[(long)v3 * D16 + lane];

    #define EMIT(tk, rk)                                                     \
    {                                                                        \
        f32x4 lo, hi;                                                        \
        lo.x = bf16_to_f32(tk[0]); lo.y = bf16_to_f32(tk[1]);                \
        lo.z = bf16_to_f32(tk[2]); lo.w = bf16_to_f32(tk[3]);                \
        hi.x = bf16_to_f32(tk[4]); hi.y = bf16_to_f32(tk[5]);                \
        hi.z = bf16_to_f32(tk[6]); hi.w = bf16_to_f32(tk[7]);                \
        long base = (long)(rk) * D4 + lane * 2;                              \
        __builtin_nontemporal_store(lo, &out[base]);                         \
        __builtin_nontemporal_store(hi, &out[base + 1]);                     \
    }

    EMIT(t0, r0);
    if (h1) EMIT(t1, r1);
    if (h2) EMIT(t2, r2);
    if (h3) EMIT(t3, r3);
    #undef EMIT
}

// Fallback (ws too small): fused f32 kernel.
__global__ __launch_bounds__(256) void fused_kernel(
    const int* __restrict__ x,
    const f32x4* __restrict__ mu,
    const f32x4* __restrict__ rho,
    const f32x4* __restrict__ eps,
    f32x4* __restrict__ out,
    int n_rows)
{
    int tid  = blockIdx.x * blockDim.x + threadIdx.x;
    int row  = tid >> 5;
    int lane = tid & 31;
    if (row >= n_rows) return;
    long src = (long)x[row] * D4 + lane;
    f32x4 m = mu[src], r = rho[src], e = eps[src];
    f32x4 o;
    o.x = m.x + softplus_f(r.x) * clip10(e.x);
    o.y = m.y + softplus_f(r.y) * clip10(e.y);
    o.z = m.z + softplus_f(r.z) * clip10(e.z);
    o.w = m.w + softplus_f(r.w) * clip10(e.w);
    out[(long)row * D4 + lane] = o;
}

extern "C" void kernel_launch(void* const* d_in, const int* in_sizes, int n_in,
                              void* d_out, int out_size, void* d_ws, size_t ws_size,
                              hipStream_t stream)
{
    const int*   x   = (const int*)  d_in[0];
    const f32x4* mu  = (const f32x4*)d_in[1];
    const f32x4* rho = (const f32x4*)d_in[2];
    const f32x4* eps = (const f32x4*)d_in[3];
    f32x4* out = (f32x4*)d_out;

    int  n_rows      = in_sizes[0];        // B*L
    long table_elems = (long)in_sizes[1];  // V*D
    size_t table_bytes_bf16 = (size_t)table_elems * sizeof(u16);
    const int block = 256;

    if (ws_size >= table_bytes_bf16) {
        long n4 = table_elems / 4;

        long threads1 = (n4 + 1) / 2;                         // 2 float4 per thread
        int grid1 = (int)((threads1 + block - 1) / block);
        sample_table_bf16_kernel<<<grid1, block, 0, stream>>>(
            mu, rho, eps, (u16x4*)d_ws, n4);

        int S = (n_rows + 3) / 4;                             // 4 rows per thread
        long threads2 = (long)S * 16;                         // 16 lanes per row
        int grid2 = (int)((threads2 + block - 1) / block);
        gather_bf16_kernel<<<grid2, block, 0, stream>>>(
            x, (const u16x8*)d_ws, out, n_rows, S);
    } else {
        long threads = (long)n_rows * 32;
        int grid = (int)((threads + block - 1) / block);
        fused_kernel<<<grid, block, 0, stream>>>(x, mu, rho, eps, out, n_rows);
    }
}

// Round 6
// 147.800 us; speedup vs baseline: 1.5132x; 1.5132x over previous
//
#include <hip/hip_runtime.h>
#include <hip/hip_bf16.h>

typedef float f32x4 __attribute__((ext_vector_type(4)));
typedef unsigned short u16;
typedef unsigned int   u32;
typedef u16 u16x4 __attribute__((ext_vector_type(4)));
typedef u16 u16x8 __attribute__((ext_vector_type(8)));

#define D4  32  // D=128 floats = 32 float4 per row; also 32 u16x4 per row

__device__ __forceinline__ float softplus_f(float r) {
    return (r > 20.0f) ? r : log1pf(__expf(r));
}
__device__ __forceinline__ float clip10(float e) {
    return fminf(fmaxf(e, -10.0f), 10.0f);
}
__device__ __forceinline__ u16 f32_to_bf16_rne(float f) {
    u32 b = __float_as_uint(f);
    b += 0x7FFFu + ((b >> 16) & 1u);   // round-to-nearest-even
    return (u16)(b >> 16);
}
__device__ __forceinline__ float bf16_to_f32(u16 h) {
    return __uint_as_float(((u32)h) << 16);
}

// Pass 1: tab[i] = bf16( mu[i] + softplus(rho[i]) * clip(eps[i]) ), 8 elems/thread.
__global__ __launch_bounds__(256) void sample_table_bf16_kernel(
    const f32x4* __restrict__ mu,
    const f32x4* __restrict__ rho,
    const f32x4* __restrict__ eps,
    u16x4* __restrict__ tab,
    long n4)
{
    long t  = (long)blockIdx.x * blockDim.x + threadIdx.x;
    long j0 = t * 2, j1 = j0 + 1;
    if (j0 >= n4) return;

    f32x4 m0 = __builtin_nontemporal_load(&mu[j0]);
    f32x4 r0 = __builtin_nontemporal_load(&rho[j0]);
    f32x4 e0 = __builtin_nontemporal_load(&eps[j0]);

    u16x4 o0;
    o0.x = f32_to_bf16_rne(m0.x + softplus_f(r0.x) * clip10(e0.x));
    o0.y = f32_to_bf16_rne(m0.y + softplus_f(r0.y) * clip10(e0.y));
    o0.z = f32_to_bf16_rne(m0.z + softplus_f(r0.z) * clip10(e0.z));
    o0.w = f32_to_bf16_rne(m0.w + softplus_f(r0.w) * clip10(e0.w));

    if (j1 < n4) {
        f32x4 m1 = __builtin_nontemporal_load(&mu[j1]);
        f32x4 r1 = __builtin_nontemporal_load(&rho[j1]);
        f32x4 e1 = __builtin_nontemporal_load(&eps[j1]);
        u16x8 o;
        o[0] = o0.x; o[1] = o0.y; o[2] = o0.z; o[3] = o0.w;
        o[4] = f32_to_bf16_rne(m1.x + softplus_f(r1.x) * clip10(e1.x));
        o[5] = f32_to_bf16_rne(m1.y + softplus_f(r1.y) * clip10(e1.y));
        o[6] = f32_to_bf16_rne(m1.z + softplus_f(r1.z) * clip10(e1.z));
        o[7] = f32_to_bf16_rne(m1.w + softplus_f(r1.w) * clip10(e1.w));
        *(u16x8*)&tab[j0] = o;           // one 16 B store
    } else {
        tab[j0] = o0;
    }
}

// Pass 2: out[row,:] = f32(tab[x[row],:]).
// Round-4 proven memory shape: 32 lanes per row, 8 B u16x4 gather per lane,
// one f32x4 store per row per lane (each store instruction across 32 lanes
// covers 512 B contiguous). 4 rows per thread, fully unrolled, static
// indices: 4 x-loads issue, then 4 independent gathers, then 4 stores.
__global__ __launch_bounds__(256) void gather_bf16_kernel(
    const int* __restrict__ x,
    const u16x4* __restrict__ tab,
    f32x4* __restrict__ out,
    int n_rows, int S)
{
    int g    = blockIdx.x * blockDim.x + threadIdx.x;
    int slot = g >> 5;        // 32 lanes per row
    int lane = g & 31;
    if (slot >= S) return;

    int  r0 = slot,        r1 = slot + S,    r2 = slot + 2*S,  r3 = slot + 3*S;
    bool h1 = (r1 < n_rows), h2 = (r2 < n_rows), h3 = (r3 < n_rows);

    int v0 = x[r0];
    int v1 = h1 ? x[r1] : v0;
    int v2 = h2 ? x[r2] : v0;
    int v3 = h3 ? x[r3] : v0;

    u16x4 t0 = tab[(long)v0 * D4 + lane];   // 4 independent gather chains
    u16x4 t1 = tab[(long)v1 * D4 + lane];
    u16x4 t2 = tab[(long)v2 * D4 + lane];
    u16x4 t3 = tab[(long)v3 * D4 + lane];

    #define EMIT(tk, rk)                                                     \
    {                                                                        \
        f32x4 o;                                                             \
        o.x = bf16_to_f32(tk.x); o.y = bf16_to_f32(tk.y);                    \
        o.z = bf16_to_f32(tk.z); o.w = bf16_to_f32(tk.w);                    \
        __builtin_nontemporal_store(o, &out[(long)(rk) * D4 + lane]);        \
    }

    EMIT(t0, r0);
    if (h1) EMIT(t1, r1);
    if (h2) EMIT(t2, r2);
    if (h3) EMIT(t3, r3);
    #undef EMIT
}

// Fallback (ws too small): fused f32 kernel.
__global__ __launch_bounds__(256) void fused_kernel(
    const int* __restrict__ x,
    const f32x4* __restrict__ mu,
    const f32x4* __restrict__ rho,
    const f32x4* __restrict__ eps,
    f32x4* __restrict__ out,
    int n_rows)
{
    int tid  = blockIdx.x * blockDim.x + threadIdx.x;
    int row  = tid >> 5;
    int lane = tid & 31;
    if (row >= n_rows) return;
    long src = (long)x[row] * D4 + lane;
    f32x4 m = mu[src], r = rho[src], e = eps[src];
    f32x4 o;
    o.x = m.x + softplus_f(r.x) * clip10(e.x);
    o.y = m.y + softplus_f(r.y) * clip10(e.y);
    o.z = m.z + softplus_f(r.z) * clip10(e.z);
    o.w = m.w + softplus_f(r.w) * clip10(e.w);
    out[(long)row * D4 + lane] = o;
}

extern "C" void kernel_launch(void* const* d_in, const int* in_sizes, int n_in,
                              void* d_out, int out_size, void* d_ws, size_t ws_size,
                              hipStream_t stream)
{
    const int*   x   = (const int*)  d_in[0];
    const f32x4* mu  = (const f32x4*)d_in[1];
    const f32x4* rho = (const f32x4*)d_in[2];
    const f32x4* eps = (const f32x4*)d_in[3];
    f32x4* out = (f32x4*)d_out;

    int  n_rows      = in_sizes[0];        // B*L
    long table_elems = (long)in_sizes[1];  // V*D
    size_t table_bytes_bf16 = (size_t)table_elems * sizeof(u16);
    const int block = 256;

    if (ws_size >= table_bytes_bf16) {
        long n4 = table_elems / 4;

        long threads1 = (n4 + 1) / 2;                         // 2 float4 per thread
        int grid1 = (int)((threads1 + block - 1) / block);
        sample_table_bf16_kernel<<<grid1, block, 0, stream>>>(
            mu, rho, eps, (u16x4*)d_ws, n4);

        int S = (n_rows + 3) / 4;                             // 4 rows per thread
        long threads2 = (long)S * 32;                         // 32 lanes per row
        int grid2 = (int)((threads2 + block - 1) / block);
        gather_bf16_kernel<<<grid2, block, 0, stream>>>(
            x, (const u16x4*)d_ws, out, n_rows, S);
    } else {
        long threads = (long)n_rows * 32;
        int grid = (int)((threads + block - 1) / block);
        fused_kernel<<<grid, block, 0, stream>>>(x, mu, rho, eps, out, n_rows);
    }
}